// Round 6
// baseline (1763.814 us; speedup 1.0000x reference)
//
#include <hip/hip_runtime.h>
#include <math.h>

// Problem constants
#define HD    1024      // hidden size
#define SEQL  512       // sequence length
#define NLAB  122       // labels
#define NWG   128       // workgroups in persistent recurrent kernel
#define TPW   512       // threads per WG
#define JPW   8         // h-columns (j) per workgroup  (NWG*JPW == HD)
#define NREP  8         // mailbox replicas (spread MALL slice hotspot)

// Workspace layout (bytes). Total ≈ 27.4 MB.
#define OFF_MSG   ((size_t)0)          // h msg: 2 parities x 8 replicas x 1024 u64 = 131072 B
#define OFF_HALL  ((size_t)131072)     // h_all: 512*1024 fp32                  = 2097152 B
#define OFF_GATES ((size_t)2228224)    // gates_x: 512*4096 fp32 (swizzled)     = 8388608 B
#define OFF_WR    ((size_t)10616832)   // W_r2: 4096*1024 fp32 (swizzled)       = 16777216 B
// end = 27394048

typedef unsigned long long u64;
typedef int v4i __attribute__((ext_vector_type(4)));

// ---------------------------------------------------------------------------
// Prep: W_r2 laid out [g][i][t] float4 (g<128, i<16, t<512) so lstm_rec WG g
// thread t stages LDS lane-contiguously and reads its 64-k slice as 16 b128.
//   t: row = t&31 (gate=row>>3, jj=row&7), kq = t>>5
//   w4[i] = W_r[R][k..k+3], k = kq*64 + i*4, R = gate*1024 + g*8 + jj
//   W_r[R][k] = W_ih[R][4096+k] + W_hh[R][k]
__global__ __launch_bounds__(256) void prep_wr(const float* __restrict__ W_ih,
                                               const float* __restrict__ W_hh,
                                               float* __restrict__ W_r2) {
    int o = blockIdx.x * 256 + threadIdx.x;   // output float4 index, < 1048576
    int g   = o >> 13;            // 16*512 float4 per g
    int i   = (o >> 9) & 15;
    int t   = o & 511;
    int row = t & 31;
    int kq  = t >> 5;
    int gate = row >> 3;
    int jj   = row & 7;
    int R = (gate << 10) + (g << 3) + jj;
    int k = (kq << 6) + (i << 2);
    float4 wa = *(const float4*)(W_ih + (size_t)R * 5120 + 4096 + k);
    float4 wb = *(const float4*)(W_hh + (size_t)R * 1024 + k);
    float4 out;
    out.x = wa.x + wb.x; out.y = wa.y + wb.y; out.z = wa.z + wb.z; out.w = wa.w + wb.w;
    *(float4*)(W_r2 + (size_t)o * 4) = out;
}

// ---------------------------------------------------------------------------
// gates_x[t][g*32 + gate*8 + jj] = b[r] + sum_k feats[t][k] * W_ih[r][k]
//   r = gate*1024 + g*8 + jj. feats = concat(x, hi). 64x64 tile, BK=16, fp32.
__global__ __launch_bounds__(256) void gates_gemm(const float* __restrict__ x,
                                                  const float* __restrict__ hi,
                                                  const float* __restrict__ W_ih,
                                                  const float* __restrict__ b_ih,
                                                  const float* __restrict__ b_hh,
                                                  float* __restrict__ gates_x) {
    __shared__ float As[16][68];
    __shared__ float Bs[16][68];
    const int tid = threadIdx.x;
    const int r0 = blockIdx.x * 64;
    const int t0 = blockIdx.y * 64;
    const int tx = tid & 15, ty = tid >> 4;
    const int l   = tid & 63;
    const int kq4 = tid >> 6;

    float acc[4][4] = {};
    for (int kb = 0; kb < 4096; kb += 16) {
        int k = kb + kq4 * 4;
        const float* asrc = (k < 2048) ? (x  + (size_t)(t0 + l) * 2048 + k)
                                       : (hi + (size_t)(t0 + l) * 2048 + (k - 2048));
        float4 a4 = *(const float4*)asrc;
        float4 b4 = *(const float4*)(W_ih + (size_t)(r0 + l) * 5120 + k);
        __syncthreads();
        As[kq4 * 4 + 0][l] = a4.x; As[kq4 * 4 + 1][l] = a4.y;
        As[kq4 * 4 + 2][l] = a4.z; As[kq4 * 4 + 3][l] = a4.w;
        Bs[kq4 * 4 + 0][l] = b4.x; Bs[kq4 * 4 + 1][l] = b4.y;
        Bs[kq4 * 4 + 2][l] = b4.z; Bs[kq4 * 4 + 3][l] = b4.w;
        __syncthreads();
        #pragma unroll
        for (int kk = 0; kk < 16; ++kk) {
            float4 av = *(const float4*)&As[kk][ty * 4];
            float4 bv = *(const float4*)&Bs[kk][tx * 4];
            float a_[4] = {av.x, av.y, av.z, av.w};
            float b_[4] = {bv.x, bv.y, bv.z, bv.w};
            #pragma unroll
            for (int i = 0; i < 4; ++i)
                #pragma unroll
                for (int j = 0; j < 4; ++j)
                    acc[i][j] += a_[i] * b_[j];
        }
    }
    int r = r0 + tx * 4;
    float bias[4];
    #pragma unroll
    for (int j = 0; j < 4; ++j) bias[j] = b_ih[r + j] + b_hh[r + j];
    int gate = r >> 10;
    int g    = (r & 1023) >> 3;
    int jj   = r & 7;             // 0 or 4
    int sidx = g * 32 + gate * 8 + jj;
    #pragma unroll
    for (int i = 0; i < 4; ++i) {
        float4 o;
        o.x = acc[i][0] + bias[0]; o.y = acc[i][1] + bias[1];
        o.z = acc[i][2] + bias[2]; o.w = acc[i][3] + bias[3];
        *(float4*)(gates_x + (size_t)(t0 + ty * 4 + i) * 4096 + sidx) = o;
    }
}

// ---------------------------------------------------------------------------
// Persistent recurrent kernel. 128 WGs x 512 threads.
// R5: single-poller-wave + replicated mailboxes. R4 evidence: time tracks
// poll-request pressure at the coherence point (65k threads hammering 64
// lines). Now ONLY wave 0 of each WG polls (64 lanes x 8 dwordx4 sc0/sc1
// coherent loads covering all 1024 tag|data words of replica g&7); waves
// 1..7 wait at the barrier — no fabric traffic, no detection skew.
// Producers publish h to 8 replicas (wave-0 lanes, one 8-B store each).
// Tag-in-word (tag s+1 <<32 | f32 bits) + parity double-buffer: unchanged.
// Weights in LDS (128 KB), prefetched to regs before the poll (lgkm under vm).
__global__ __launch_bounds__(512, 1) void lstm_rec(const float* __restrict__ gates_x,
                                                   const float* __restrict__ W_r2,
                                                   float* __restrict__ h_all,
                                                   u64* h_msg) {
    const int g    = blockIdx.x;
    const int tid  = threadIdx.x;
    const int row  = tid & 31;    // gate = row>>3, jj = row&7
    const int kq   = tid >> 5;    // k-slice [kq*64, kq*64+64)
    const int wv   = tid >> 6;    // wave id 0..7
    const int lane = tid & 63;
    __shared__ float4 W_lds[16][TPW];   // 128 KB, lane-contiguous
    __shared__ float4 h_s4[256];        // h_{s-1}; h_s4[q] = h[4q..4q+3]
    __shared__ float  partial[8][36];   // [wave][row]
    float* h_sf = (float*)h_s4;

    // one-time stage: global (coalesced) -> LDS
    {
        const float4* Wp = (const float4*)W_r2 + (size_t)g * 8192;
        #pragma unroll
        for (int i = 0; i < 16; ++i)
            W_lds[i][tid] = Wp[i * TPW + tid];
    }
    __syncthreads();

    float c = 0.f;               // cell state, meaningful in wave-0 lanes 0..7
    int budget = 2000000;        // anti-hang poll budget (sweeps)

    for (int s = 0; s < SEQL; ++s) {
        asm volatile("" ::: "memory");
        // 1) weight ds_reads issue now, complete under the poll (lgkm vs vm)
        float4 w[16];
        #pragma unroll
        for (int i = 0; i < 16; ++i)
            w[i] = W_lds[i][tid];
        asm volatile("" ::: "memory");

        // 2) independent gx prefetch (wave-0 lanes 0..31 consume later)
        float gx = 0.f;
        if (tid < 32)
            gx = gates_x[(size_t)s * 4096 + g * 32 + tid];

        // 3) wave 0 polls replica g&7: lane owns 16 u64 (one 128-B line),
        //    8 coherent dwordx4 loads per sweep; wave-wide __all on 16 tags.
        if (wv == 0) {
            const u64* base = h_msg + ((size_t)((s & 1) * NREP + (g & 7)) * HD) + lane * 16;
            unsigned long long addr = (unsigned long long)base;
            const int want = (int)s;
            v4i a0, a1, a2, a3, a4, a5, a6, a7;
            for (;;) {
                asm volatile(
                    "global_load_dwordx4 %0, %8, off sc0 sc1\n\t"
                    "global_load_dwordx4 %1, %8, off offset:16 sc0 sc1\n\t"
                    "global_load_dwordx4 %2, %8, off offset:32 sc0 sc1\n\t"
                    "global_load_dwordx4 %3, %8, off offset:48 sc0 sc1\n\t"
                    "global_load_dwordx4 %4, %8, off offset:64 sc0 sc1\n\t"
                    "global_load_dwordx4 %5, %8, off offset:80 sc0 sc1\n\t"
                    "global_load_dwordx4 %6, %8, off offset:96 sc0 sc1\n\t"
                    "global_load_dwordx4 %7, %8, off offset:112 sc0 sc1\n\t"
                    "s_waitcnt vmcnt(0)"
                    : "=&v"(a0), "=&v"(a1), "=&v"(a2), "=&v"(a3),
                      "=&v"(a4), "=&v"(a5), "=&v"(a6), "=&v"(a7)
                    : "v"(addr)
                    : "memory");
                int ok = (a0.y == want) & (a0.w == want) & (a1.y == want) & (a1.w == want)
                       & (a2.y == want) & (a2.w == want) & (a3.y == want) & (a3.w == want)
                       & (a4.y == want) & (a4.w == want) & (a5.y == want) & (a5.w == want)
                       & (a6.y == want) & (a6.w == want) & (a7.y == want) & (a7.w == want);
                if (__all(ok)) break;
                if (--budget < 0) break;
            }
            // unpack 16 data dwords -> LDS h[lane*16 .. lane*16+15]
            float2* h2 = (float2*)(h_sf + lane * 16);
            h2[0] = make_float2(__int_as_float(a0.x), __int_as_float(a0.z));
            h2[1] = make_float2(__int_as_float(a1.x), __int_as_float(a1.z));
            h2[2] = make_float2(__int_as_float(a2.x), __int_as_float(a2.z));
            h2[3] = make_float2(__int_as_float(a3.x), __int_as_float(a3.z));
            h2[4] = make_float2(__int_as_float(a4.x), __int_as_float(a4.z));
            h2[5] = make_float2(__int_as_float(a5.x), __int_as_float(a5.z));
            h2[6] = make_float2(__int_as_float(a6.x), __int_as_float(a6.z));
            h2[7] = make_float2(__int_as_float(a7.x), __int_as_float(a7.z));
        }
        __syncthreads();

        // 4) matvec: 1 row x 64 k per thread (h broadcast across 32 lanes)
        float a0 = 0.f, a1 = 0.f, a2 = 0.f, a3 = 0.f;
        #pragma unroll
        for (int i = 0; i < 16; ++i) {
            float4 h4 = h_s4[kq * 16 + i];
            a0 += w[i].x * h4.x;
            a1 += w[i].y * h4.y;
            a2 += w[i].z * h4.z;
            a3 += w[i].w * h4.w;
        }
        float p = (a0 + a1) + (a2 + a3);
        p += __shfl_xor(p, 32, 64);          // fold the wave's two kq halves
        if ((tid & 32) == 0)
            partial[wv][row] = p;            // lanes 0..31 of each wave
        __syncthreads();

        // 5) wave-0 tail: final 8-way sum, activations, publish to 8 replicas
        if (wv == 0) {
            float hval = 0.f;
            if (lane < 32) {
                float sum = gx;
                #pragma unroll
                for (int q = 0; q < 8; ++q) sum += partial[q][lane];
                int jj = lane & 7;
                float vf = __shfl(sum,  8 + jj, 64);
                float vg = __shfl(sum, 16 + jj, 64);
                float vo = __shfl(sum, 24 + jj, 64);
                if (lane < 8) {
                    float si = 1.f / (1.f + __expf(-sum));
                    float sf = 1.f / (1.f + __expf(-vf));
                    float so = 1.f / (1.f + __expf(-vo));
                    float tg = 2.f / (1.f + __expf(-2.f * vg)) - 1.f;   // tanh
                    c = sf * c + si * tg;
                    float th = 2.f / (1.f + __expf(-2.f * c)) - 1.f;    // tanh
                    hval = so * th;
                    h_all[(size_t)s * HD + g * JPW + lane] = hval;
                }
            }
            // every lane stores one replica copy: replica = lane>>3, col = lane&7
            float hv = __shfl(hval, lane & 7, 64);
            u64 m = ((u64)(unsigned)(s + 1) << 32) | (u64)__float_as_uint(hv);
            int rep = lane >> 3;
            __hip_atomic_store(h_msg + (size_t)(((s + 1) & 1) * NREP + rep) * HD
                                     + g * JPW + (lane & 7),
                               m, __ATOMIC_RELAXED, __HIP_MEMORY_SCOPE_AGENT);
        }
        // no trailing barrier: partial[] / h_s4 next written only after the
        // barriers of iteration s+1
    }
}

// ---------------------------------------------------------------------------
// out[t][lab] = b_fc[lab] + sum_k h_all[t][k] * W_fc[lab][k]
__global__ __launch_bounds__(128) void fc_out(const float* __restrict__ h_all,
                                              const float* __restrict__ W_fc,
                                              const float* __restrict__ b_fc,
                                              float* __restrict__ out) {
    const int t = blockIdx.x;
    const int tid = threadIdx.x;
    __shared__ float4 h_s[256];
    const float4* hsrc = (const float4*)(h_all + (size_t)t * HD);
    h_s[tid] = hsrc[tid];
    h_s[tid + 128] = hsrc[tid + 128];
    __syncthreads();
    if (tid < NLAB) {
        float acc = b_fc[tid];
        const float4* wp = (const float4*)(W_fc + (size_t)tid * HD);
        #pragma unroll 8
        for (int k4 = 0; k4 < 256; ++k4) {
            float4 w = wp[k4];
            float4 h = h_s[k4];
            acc += w.x*h.x + w.y*h.y + w.z*h.z + w.w*h.w;
        }
        out[(size_t)t * NLAB + tid] = acc;
    }
}

// ---------------------------------------------------------------------------
extern "C" void kernel_launch(void* const* d_in, const int* in_sizes, int n_in,
                              void* d_out, int out_size, void* d_ws, size_t ws_size,
                              hipStream_t stream) {
    const float* x    = (const float*)d_in[0];
    const float* hi   = (const float*)d_in[1];
    const float* W_ih = (const float*)d_in[2];
    const float* W_hh = (const float*)d_in[3];
    const float* b_ih = (const float*)d_in[4];
    const float* b_hh = (const float*)d_in[5];
    const float* W_fc = (const float*)d_in[6];
    const float* b_fc = (const float*)d_in[7];
    float* out = (float*)d_out;

    char* ws = (char*)d_ws;
    u64*   h_msg   = (u64*)(ws + OFF_MSG);
    float* h_all   = (float*)(ws + OFF_HALL);
    float* gates_x = (float*)(ws + OFF_GATES);
    float* W_r2    = (float*)(ws + OFF_WR);

    // zero all mailbox replicas: h_{-1}=0 with tag 0 (ws re-poisoned each call)
    hipMemsetAsync(d_ws, 0, 131072, stream);

    prep_wr<<<4096, 256, 0, stream>>>(W_ih, W_hh, W_r2);

    dim3 gg(64, 8);
    gates_gemm<<<gg, 256, 0, stream>>>(x, hi, W_ih, b_ih, b_hh, gates_x);

    lstm_rec<<<NWG, TPW, 0, stream>>>(gates_x, W_r2, h_all, h_msg);

    fc_out<<<SEQL, 128, 0, stream>>>(h_all, W_fc, b_fc, out);
}

// Round 7
// 1583.215 us; speedup vs baseline: 1.1141x; 1.1141x over previous
//
#include <hip/hip_runtime.h>
#include <hip/hip_fp16.h>
#include <math.h>

// Problem constants
#define HD    1024      // hidden size
#define SEQL  512       // sequence length
#define NLAB  122       // labels
#define NWG   128       // workgroups in persistent recurrent kernel
#define TPW   512       // threads per WG
#define JPW   8         // h-columns (j) per workgroup  (NWG*JPW == HD)
#define NMSG  512       // mailbox words per parity (2 fp16 h per word)

// Workspace layout (bytes). Total ≈ 27.3 MB.
#define OFF_MSG   ((size_t)0)          // h msg: 2 parities x 512 u64           = 8192 B
#define OFF_HALL  ((size_t)16384)      // h_all: 512*1024 fp32                  = 2097152 B
#define OFF_GATES ((size_t)2113536)    // gates_x: 512*4096 fp32 (swizzled)     = 8388608 B
#define OFF_WR    ((size_t)10502144)   // W_r2: 4096*1024 fp32 (swizzled)       = 16777216 B
// end = 27279360

typedef unsigned long long u64;

// ---------------------------------------------------------------------------
// Prep: W_r2 laid out [g][i][t] float4 (g<128, i<16, t<512) so lstm_rec WG g
// thread t stages LDS lane-contiguously and reads its 64-k slice as 16 b128.
//   t: row = t&31 (gate=row>>3, jj=row&7), kq = t>>5
//   w4[i] = W_r[R][k..k+3], k = kq*64 + i*4, R = gate*1024 + g*8 + jj
//   W_r[R][k] = W_ih[R][4096+k] + W_hh[R][k]
__global__ __launch_bounds__(256) void prep_wr(const float* __restrict__ W_ih,
                                               const float* __restrict__ W_hh,
                                               float* __restrict__ W_r2) {
    int o = blockIdx.x * 256 + threadIdx.x;   // output float4 index, < 1048576
    int g   = o >> 13;            // 16*512 float4 per g
    int i   = (o >> 9) & 15;
    int t   = o & 511;
    int row = t & 31;
    int kq  = t >> 5;
    int gate = row >> 3;
    int jj   = row & 7;
    int R = (gate << 10) + (g << 3) + jj;
    int k = (kq << 6) + (i << 2);
    float4 wa = *(const float4*)(W_ih + (size_t)R * 5120 + 4096 + k);
    float4 wb = *(const float4*)(W_hh + (size_t)R * 1024 + k);
    float4 out;
    out.x = wa.x + wb.x; out.y = wa.y + wb.y; out.z = wa.z + wb.z; out.w = wa.w + wb.w;
    *(float4*)(W_r2 + (size_t)o * 4) = out;
}

// ---------------------------------------------------------------------------
// gates_x[t][g*32 + gate*8 + jj] = b[r] + sum_k feats[t][k] * W_ih[r][k]
//   r = gate*1024 + g*8 + jj. feats = concat(x, hi). 64x64 tile, BK=16, fp32.
__global__ __launch_bounds__(256) void gates_gemm(const float* __restrict__ x,
                                                  const float* __restrict__ hi,
                                                  const float* __restrict__ W_ih,
                                                  const float* __restrict__ b_ih,
                                                  const float* __restrict__ b_hh,
                                                  float* __restrict__ gates_x) {
    __shared__ float As[16][68];
    __shared__ float Bs[16][68];
    const int tid = threadIdx.x;
    const int r0 = blockIdx.x * 64;
    const int t0 = blockIdx.y * 64;
    const int tx = tid & 15, ty = tid >> 4;
    const int l   = tid & 63;
    const int kq4 = tid >> 6;

    float acc[4][4] = {};
    for (int kb = 0; kb < 4096; kb += 16) {
        int k = kb + kq4 * 4;
        const float* asrc = (k < 2048) ? (x  + (size_t)(t0 + l) * 2048 + k)
                                       : (hi + (size_t)(t0 + l) * 2048 + (k - 2048));
        float4 a4 = *(const float4*)asrc;
        float4 b4 = *(const float4*)(W_ih + (size_t)(r0 + l) * 5120 + k);
        __syncthreads();
        As[kq4 * 4 + 0][l] = a4.x; As[kq4 * 4 + 1][l] = a4.y;
        As[kq4 * 4 + 2][l] = a4.z; As[kq4 * 4 + 3][l] = a4.w;
        Bs[kq4 * 4 + 0][l] = b4.x; Bs[kq4 * 4 + 1][l] = b4.y;
        Bs[kq4 * 4 + 2][l] = b4.z; Bs[kq4 * 4 + 3][l] = b4.w;
        __syncthreads();
        #pragma unroll
        for (int kk = 0; kk < 16; ++kk) {
            float4 av = *(const float4*)&As[kk][ty * 4];
            float4 bv = *(const float4*)&Bs[kk][tx * 4];
            float a_[4] = {av.x, av.y, av.z, av.w};
            float b_[4] = {bv.x, bv.y, bv.z, bv.w};
            #pragma unroll
            for (int i = 0; i < 4; ++i)
                #pragma unroll
                for (int j = 0; j < 4; ++j)
                    acc[i][j] += a_[i] * b_[j];
        }
    }
    int r = r0 + tx * 4;
    float bias[4];
    #pragma unroll
    for (int j = 0; j < 4; ++j) bias[j] = b_ih[r + j] + b_hh[r + j];
    int gate = r >> 10;
    int g    = (r & 1023) >> 3;
    int jj   = r & 7;             // 0 or 4
    int sidx = g * 32 + gate * 8 + jj;
    #pragma unroll
    for (int i = 0; i < 4; ++i) {
        float4 o;
        o.x = acc[i][0] + bias[0]; o.y = acc[i][1] + bias[1];
        o.z = acc[i][2] + bias[2]; o.w = acc[i][3] + bias[3];
        *(float4*)(gates_x + (size_t)(t0 + ty * 4 + i) * 4096 + sidx) = o;
    }
}

// ---------------------------------------------------------------------------
// Persistent recurrent kernel. 128 WGs x 512 threads (R4 protocol skeleton —
// the best measured). R6 change: fp16-packed mailbox. Word w of parity p =
//   tag(s+1)<<32 | fp16(h[2w+1])<<16 | fp16(h[2w])
// -> whole h vector = 512 u64 = 4 KB (half the lines of R4), each thread
// polls exactly ONE word, single-sample: 512 req/WG/sweep = 4x fewer than
// R4's 2048 (R5 taught: publish width and sweep payload hurt; per-thread
// detect + barrier is the right shape). Publish = 4 stores/WG/step.
// Weights in LDS (128 KB), prefetched to regs before the poll (lgkm under vm).
__global__ __launch_bounds__(512, 1) void lstm_rec(const float* __restrict__ gates_x,
                                                   const float* __restrict__ W_r2,
                                                   float* __restrict__ h_all,
                                                   u64* h_msg) {
    const int g    = blockIdx.x;
    const int tid  = threadIdx.x;
    const int row  = tid & 31;    // gate = row>>3, jj = row&7
    const int kq   = tid >> 5;    // k-slice [kq*64, kq*64+64)
    const int wv   = tid >> 6;    // wave id 0..7
    const int lane = tid & 63;
    __shared__ float4 W_lds[16][TPW];   // 128 KB, lane-contiguous
    __shared__ float4 h_s4[256];        // h_{s-1}; h_s4[q] = h[4q..4q+3]
    __shared__ float  partial[8][36];   // [wave][row]
    float* h_sf = (float*)h_s4;

    // one-time stage: global (coalesced) -> LDS
    {
        const float4* Wp = (const float4*)W_r2 + (size_t)g * 8192;
        #pragma unroll
        for (int i = 0; i < 16; ++i)
            W_lds[i][tid] = Wp[i * TPW + tid];
    }
    __syncthreads();

    float c = 0.f;               // cell state, meaningful in wave-0 lanes 0..7
    int budget = 4000000;        // anti-hang poll budget (sweeps)

    for (int s = 0; s < SEQL; ++s) {
        asm volatile("" ::: "memory");
        // 1) weight ds_reads issue now, complete under the poll (lgkm vs vm)
        float4 w[16];
        #pragma unroll
        for (int i = 0; i < 16; ++i)
            w[i] = W_lds[i][tid];
        asm volatile("" ::: "memory");

        // 2) independent gx prefetch (wave-0 lanes 0..31 consume later)
        float gx = 0.f;
        if (tid < 32)
            gx = gates_x[(size_t)s * 4096 + g * 32 + tid];

        // 3) poll h_{s-1}: thread tid owns mailbox word tid (h[2tid], h[2tid+1])
        {
            const u64* buf = h_msg + (size_t)(s & 1) * NMSG + tid;
            const unsigned want = (unsigned)s;
            u64 v;
            for (;;) {
                v = __hip_atomic_load(buf, __ATOMIC_RELAXED, __HIP_MEMORY_SCOPE_AGENT);
                if ((unsigned)(v >> 32) == want) break;
                if (--budget < 0) break;
            }
            unsigned lo = (unsigned)v;
            __half2 hh = *(__half2*)&lo;
            float2 f = __half22float2(hh);
            h_sf[2 * tid + 0] = f.x;
            h_sf[2 * tid + 1] = f.y;
        }
        __syncthreads();

        // 4) matvec: 1 row x 64 k per thread (h broadcast across 32 lanes)
        float a0 = 0.f, a1 = 0.f, a2 = 0.f, a3 = 0.f;
        #pragma unroll
        for (int i = 0; i < 16; ++i) {
            float4 h4 = h_s4[kq * 16 + i];
            a0 += w[i].x * h4.x;
            a1 += w[i].y * h4.y;
            a2 += w[i].z * h4.z;
            a3 += w[i].w * h4.w;
        }
        float p = (a0 + a1) + (a2 + a3);
        p += __shfl_xor(p, 32, 64);          // fold the wave's two kq halves
        if ((tid & 32) == 0)
            partial[wv][row] = p;            // lanes 0..31 of each wave
        __syncthreads();

        // 5) wave-0 tail: final 8-way sum, activations, publish 4 packed words
        if (wv == 0) {
            float hval = 0.f;
            if (lane < 32) {
                float sum = gx;
                #pragma unroll
                for (int q = 0; q < 8; ++q) sum += partial[q][lane];
                int jj = lane & 7;
                float vf = __shfl(sum,  8 + jj, 64);
                float vg = __shfl(sum, 16 + jj, 64);
                float vo = __shfl(sum, 24 + jj, 64);
                if (lane < 8) {
                    float si = 1.f / (1.f + __expf(-sum));
                    float sf = 1.f / (1.f + __expf(-vf));
                    float so = 1.f / (1.f + __expf(-vo));
                    float tg = 2.f / (1.f + __expf(-2.f * vg)) - 1.f;   // tanh
                    c = sf * c + si * tg;
                    float th = 2.f / (1.f + __expf(-2.f * c)) - 1.f;    // tanh
                    hval = so * th;
                    h_all[(size_t)s * HD + g * JPW + lane] = hval;      // fp32
                }
            }
            // pack pairs: lane L<4 publishes word g*4+L = (tag | fp16 pair)
            float h0 = __shfl(hval, (lane & 3) * 2 + 0, 64);
            float h1 = __shfl(hval, (lane & 3) * 2 + 1, 64);
            if (lane < 4) {
                __half2 ph = __floats2half2_rn(h0, h1);
                unsigned pu = *(unsigned*)&ph;
                u64 m = ((u64)(unsigned)(s + 1) << 32) | (u64)pu;
                __hip_atomic_store(h_msg + (size_t)((s + 1) & 1) * NMSG + g * 4 + lane,
                                   m, __ATOMIC_RELAXED, __HIP_MEMORY_SCOPE_AGENT);
            }
        }
        // no trailing barrier: partial[] / h_s4 next written only after the
        // barriers of iteration s+1
    }
}

// ---------------------------------------------------------------------------
// out[t][lab] = b_fc[lab] + sum_k h_all[t][k] * W_fc[lab][k]
__global__ __launch_bounds__(128) void fc_out(const float* __restrict__ h_all,
                                              const float* __restrict__ W_fc,
                                              const float* __restrict__ b_fc,
                                              float* __restrict__ out) {
    const int t = blockIdx.x;
    const int tid = threadIdx.x;
    __shared__ float4 h_s[256];
    const float4* hsrc = (const float4*)(h_all + (size_t)t * HD);
    h_s[tid] = hsrc[tid];
    h_s[tid + 128] = hsrc[tid + 128];
    __syncthreads();
    if (tid < NLAB) {
        float acc = b_fc[tid];
        const float4* wp = (const float4*)(W_fc + (size_t)tid * HD);
        #pragma unroll 8
        for (int k4 = 0; k4 < 256; ++k4) {
            float4 w = wp[k4];
            float4 h = h_s[k4];
            acc += w.x*h.x + w.y*h.y + w.z*h.z + w.w*h.w;
        }
        out[(size_t)t * NLAB + tid] = acc;
    }
}

// ---------------------------------------------------------------------------
extern "C" void kernel_launch(void* const* d_in, const int* in_sizes, int n_in,
                              void* d_out, int out_size, void* d_ws, size_t ws_size,
                              hipStream_t stream) {
    const float* x    = (const float*)d_in[0];
    const float* hi   = (const float*)d_in[1];
    const float* W_ih = (const float*)d_in[2];
    const float* W_hh = (const float*)d_in[3];
    const float* b_ih = (const float*)d_in[4];
    const float* b_hh = (const float*)d_in[5];
    const float* W_fc = (const float*)d_in[6];
    const float* b_fc = (const float*)d_in[7];
    float* out = (float*)d_out;

    char* ws = (char*)d_ws;
    u64*   h_msg   = (u64*)(ws + OFF_MSG);
    float* h_all   = (float*)(ws + OFF_HALL);
    float* gates_x = (float*)(ws + OFF_GATES);
    float* W_r2    = (float*)(ws + OFF_WR);

    // zero the mailbox: h_{-1}=0 with tag 0 (ws re-poisoned 0xAA each call)
    hipMemsetAsync(d_ws, 0, 8192, stream);

    prep_wr<<<4096, 256, 0, stream>>>(W_ih, W_hh, W_r2);

    dim3 gg(64, 8);
    gates_gemm<<<gg, 256, 0, stream>>>(x, hi, W_ih, b_ih, b_hh, gates_x);

    lstm_rec<<<NWG, TPW, 0, stream>>>(gates_x, W_r2, h_all, h_msg);

    fc_out<<<SEQL, 128, 0, stream>>>(h_all, W_fc, b_fc, out);
}